// Round 4
// baseline (369.502 us; speedup 1.0000x reference)
//
#include <hip/hip_runtime.h>
#include <math.h>

// Problem constants (from reference)
#define NPTS   65536        // 256*256
#define NB     5            // batch of x
#define NX     25
#define NY     7
#define NZ     6
#define NW     5
#define FG     (NB*NX*NY*NZ*NW)       // 26250 f_grid elements
#define GRID_ELEMS 52500000LL         // 2000 * FG
// out layout: [0]=loss, [1 .. 65536]=theta[0], [65537 ..]=grid_new
// out_grid float index 65537 == 1 (mod 4)  ->  dst 16B-aligned iff e == 3 (mod 4)
#define HEAD   3LL                    // elements 0,1,2 handled scalar
#define NCH    ((GRID_ELEMS - HEAD) / 4)   // 13,124,999 full chunks
#define TAIL_E (HEAD + 4*NCH)              // 52,499,999 (single tail element)
// K2 launch geometry: 16384 blocks x 256 threads
#define K2_T   4194304LL                   // total threads
// 3*K2_T = 12,582,912 <= NCH; remainder 542,087 threads take a 4th chunk
// ws layout: [0..4]=s[n], [5]=sum|theta|, [6]=sum(f*W4)

typedef float f4  __attribute__((ext_vector_type(4)));               // 16B aligned
typedef float f4u __attribute__((ext_vector_type(4), aligned(4)));   // 4B aligned

// Kernel A: s[n] = sum_i x[n,i]*theta[i] (n=0..4), ws[5] = sum |theta|,
// and copy theta -> out_theta.
__global__ void reduce_kernel(const float* __restrict__ x,
                              const float* __restrict__ theta,
                              float* __restrict__ out_theta,
                              float* __restrict__ ws) {
    __shared__ float smem[4 * 6];   // 4 waves x 6 partials
    int idx = blockIdx.x * blockDim.x + threadIdx.x;   // 0..65535
    float t = theta[idx];
    out_theta[idx] = t;

    float vals[6];
#pragma unroll
    for (int n = 0; n < 5; ++n) vals[n] = x[n * NPTS + idx] * t;
    vals[5] = fabsf(t);

    int lane = threadIdx.x & 63;
    int wave = threadIdx.x >> 6;
#pragma unroll
    for (int k = 0; k < 6; ++k) {
        float v = vals[k];
#pragma unroll
        for (int off = 32; off > 0; off >>= 1) v += __shfl_down(v, off, 64);
        if (lane == 0) smem[wave * 6 + k] = v;
    }
    __syncthreads();
    if (threadIdx.x < 6) {
        float acc = smem[threadIdx.x] + smem[6 + threadIdx.x] +
                    smem[12 + threadIdx.x] + smem[18 + threadIdx.x];
        atomicAdd(&ws[threadIdx.x], acc);
    }
}

// f_grid element evaluation (identical arithmetic to the verified kernel)
__device__ __forceinline__ float fgrid_eval(const float* s, int e2, float* w4out) {
    int d  = e2 % NW;
    int cz = (e2 / NW) % NZ;
    int b  = (e2 / (NW * NZ)) % NY;
    int a  = (e2 / (NW * NZ * NY)) % NX;
    int n  = e2 / (NW * NZ * NY * NX);

    const float PI2 = 6.283185307179586f;
    const float dxq = PI2 / 24.0f;
    const float dy = 0.03f;         // 0.18/6
    const float dz = 0.036f;        // 0.18/5
    const float dw = 0.05f;         // 0.2/4

    float xv = PI2 * (float)a / 24.0f;
    float cv = cosf(xv);
    float yv = -0.09f + dy * (float)b;
    float zv = -0.09f + dz * (float)cz;
    float wv = 0.9f + dw * (float)d;

    float arg = s[n] * cv * wv + yv + zv;
    float f = expf(-arg * arg);

    *w4out = dxq * ((a == 0 || a == NX - 1) ? 0.5f : 1.0f)
           * dy  * ((b == 0 || b == NY - 1) ? 0.5f : 1.0f)
           * dz  * ((cz == 0 || cz == NZ - 1) ? 0.5f : 1.0f)
           * dw  * ((d == 0 || d == NW - 1) ? 0.5f : 1.0f);
    return f;
}

// Kernel B (fused, loop-free MLP variant): each thread owns chunks
// {t, t+T, t+2T} (+ t+3T for the first 542,087 threads). All nt loads
// issue before any store -> 4 outstanding 16B loads/thread. Chunks
// overlapping slot j compute f_grid instead and accumulate loss.
// Stores 16B-aligned (chunks start at e==3 mod 4); loads take the 4B
// misalignment (exonerated in R0/R1).
__global__ void __launch_bounds__(256)
copy_fgrid_kernel(const float* __restrict__ grid,
                  float* __restrict__ out_grid,      // out + 1 + NPTS
                  const float* __restrict__ ws_in,
                  float* __restrict__ ws_out,
                  const int* __restrict__ jptr) {
    const int j = *jptr;
    const long long jlo = (long long)j * FG;
    const long long jhi = jlo + FG;

    float s[5];
#pragma unroll
    for (int n = 0; n < 5; ++n) s[n] = ws_in[n];

    const long long t = (long long)blockIdx.x * blockDim.x + threadIdx.x;
    const long long c0 = t;
    const long long c1 = t + K2_T;
    const long long c2 = t + 2 * K2_T;
    const long long c3 = t + 3 * K2_T;
    const bool has3 = (c3 < NCH);

    // all loads up front (max MLP)
    f4 v0 = (f4)__builtin_nontemporal_load((const f4u*)(grid + HEAD + 4 * c0));
    f4 v1 = (f4)__builtin_nontemporal_load((const f4u*)(grid + HEAD + 4 * c1));
    f4 v2 = (f4)__builtin_nontemporal_load((const f4u*)(grid + HEAD + 4 * c2));
    f4 v3 = has3
        ? (f4)__builtin_nontemporal_load((const f4u*)(grid + HEAD + 4 * c3))
        : (f4){0.f, 0.f, 0.f, 0.f};

    // rare path: patch chunks overlapping slot j
    float local = 0.0f;
    auto patch = [&](f4& v, long long c) {
        const long long base = HEAD + 4 * c;
        if (base + 3 >= jlo && base < jhi) {
#pragma unroll
            for (int q = 0; q < 4; ++q) {
                long long e = base + q;
                if (e >= jlo && e < jhi) {
                    float w4;
                    float f = fgrid_eval(s, (int)(e - jlo), &w4);
                    v[q] = f;
                    local += f * w4;
                }
            }
        }
    };
    patch(v0, c0);
    patch(v1, c1);
    patch(v2, c2);
    if (has3) patch(v3, c3);

    // all stores (16B-aligned, nontemporal)
    __builtin_nontemporal_store(v0, (f4*)(out_grid + HEAD + 4 * c0));
    __builtin_nontemporal_store(v1, (f4*)(out_grid + HEAD + 4 * c1));
    __builtin_nontemporal_store(v2, (f4*)(out_grid + HEAD + 4 * c2));
    if (has3)
        __builtin_nontemporal_store(v3, (f4*)(out_grid + HEAD + 4 * c3));

    // head (e=0,1,2) and tail (e=TAIL_E) handled by a single thread
    if (blockIdx.x == 0 && threadIdx.x == 0) {
        const long long edge[4] = {0, 1, 2, TAIL_E};
#pragma unroll
        for (int k = 0; k < 4; ++k) {
            long long e = edge[k];
            float v = grid[e];
            if (e >= jlo && e < jhi) {
                float w4;
                float f = fgrid_eval(s, (int)(e - jlo), &w4);
                v = f;
                local += f * w4;
            }
            out_grid[e] = v;
        }
    }

    // wave-level reduction of loss contributions, one atomic per wave
#pragma unroll
    for (int off = 32; off > 0; off >>= 1) local += __shfl_down(local, off, 64);
    if ((threadIdx.x & 63) == 0 && local != 0.0f) atomicAdd(&ws_out[6], local);
}

// Kernel C: finalize loss
__global__ void finalize_kernel(const float* __restrict__ ws,
                                float* __restrict__ out) {
    out[0] = ws[6] - 0.5f * ws[5];
}

extern "C" void kernel_launch(void* const* d_in, const int* in_sizes, int n_in,
                              void* d_out, int out_size, void* d_ws, size_t ws_size,
                              hipStream_t stream) {
    const float* x     = (const float*)d_in[0];   // [5,256,256]
    const float* theta = (const float*)d_in[1];   // [1,256,256]
    const float* grid  = (const float*)d_in[2];   // [2000,5,25,7,6,5]
    const int*   jptr  = (const int*)d_in[3];     // scalar

    float* out = (float*)d_out;
    float* ws  = (float*)d_ws;

    // zero reduction scratch (ws is poisoned 0xAA each launch)
    hipMemsetAsync(ws, 0, 7 * sizeof(float), stream);

    // K1: projections + |theta| sum + theta passthrough
    reduce_kernel<<<NPTS / 256, 256, 0, stream>>>(x, theta, out + 1, ws);

    // K2: fused copy + f_grid scatter + loss partial (loop-free, nt, MLP=4)
    copy_fgrid_kernel<<<16384, 256, 0, stream>>>(grid, out + 1 + NPTS,
                                                 ws, ws, jptr);

    // K3: finalize loss
    finalize_kernel<<<1, 1, 0, stream>>>(ws, out);
}

// Round 5
// 353.478 us; speedup vs baseline: 1.0453x; 1.0453x over previous
//
#include <hip/hip_runtime.h>
#include <math.h>

// Problem constants (from reference)
#define NPTS   65536        // 256*256
#define NB     5            // batch of x
#define NX     25
#define NY     7
#define NZ     6
#define NW     5
#define FG     (NB*NX*NY*NZ*NW)       // 26250 f_grid elements
#define GRID_ELEMS 52500000LL         // 2000 * FG
// out layout: [0]=loss, [1 .. 65536]=theta[0], [65537 ..]=grid_new
// out_grid float index 65537 == 1 (mod 4)  ->  dst 16B-aligned iff e == 3 (mod 4)
#define HEAD   3LL                    // elements 0,1,2 handled scalar
#define NCH    ((GRID_ELEMS - HEAD) / 4)   // 13,124,999 full chunks
#define TAIL_E (HEAD + 4*NCH)              // 52,499,999 (single tail element)
// ws layout: [0..4]=s[n], [5]=sum|theta|, [6]=sum(f*W4)

typedef float f4  __attribute__((ext_vector_type(4)));               // 16B aligned
typedef float f4u __attribute__((ext_vector_type(4), aligned(4)));   // 4B aligned

// Kernel A: s[n] = sum_i x[n,i]*theta[i] (n=0..4), ws[5] = sum |theta|,
// and copy theta -> out_theta.
__global__ void reduce_kernel(const float* __restrict__ x,
                              const float* __restrict__ theta,
                              float* __restrict__ out_theta,
                              float* __restrict__ ws) {
    __shared__ float smem[4 * 6];   // 4 waves x 6 partials
    int idx = blockIdx.x * blockDim.x + threadIdx.x;   // 0..65535
    float t = theta[idx];
    out_theta[idx] = t;

    float vals[6];
#pragma unroll
    for (int n = 0; n < 5; ++n) vals[n] = x[n * NPTS + idx] * t;
    vals[5] = fabsf(t);

    int lane = threadIdx.x & 63;
    int wave = threadIdx.x >> 6;
#pragma unroll
    for (int k = 0; k < 6; ++k) {
        float v = vals[k];
#pragma unroll
        for (int off = 32; off > 0; off >>= 1) v += __shfl_down(v, off, 64);
        if (lane == 0) smem[wave * 6 + k] = v;
    }
    __syncthreads();
    if (threadIdx.x < 6) {
        float acc = smem[threadIdx.x] + smem[6 + threadIdx.x] +
                    smem[12 + threadIdx.x] + smem[18 + threadIdx.x];
        atomicAdd(&ws[threadIdx.x], acc);
    }
}

// f_grid element evaluation (identical arithmetic to the verified kernel)
__device__ __forceinline__ float fgrid_eval(const float* s, int e2, float* w4out) {
    int d  = e2 % NW;
    int cz = (e2 / NW) % NZ;
    int b  = (e2 / (NW * NZ)) % NY;
    int a  = (e2 / (NW * NZ * NY)) % NX;
    int n  = e2 / (NW * NZ * NY * NX);

    const float PI2 = 6.283185307179586f;
    const float dxq = PI2 / 24.0f;
    const float dy = 0.03f;         // 0.18/6
    const float dz = 0.036f;        // 0.18/5
    const float dw = 0.05f;         // 0.2/4

    float xv = PI2 * (float)a / 24.0f;
    float cv = cosf(xv);
    float yv = -0.09f + dy * (float)b;
    float zv = -0.09f + dz * (float)cz;
    float wv = 0.9f + dw * (float)d;

    float arg = s[n] * cv * wv + yv + zv;
    float f = expf(-arg * arg);

    *w4out = dxq * ((a == 0 || a == NX - 1) ? 0.5f : 1.0f)
           * dy  * ((b == 0 || b == NY - 1) ? 0.5f : 1.0f)
           * dz  * ((cz == 0 || cz == NZ - 1) ? 0.5f : 1.0f)
           * dw  * ((d == 0 || d == NW - 1) ? 0.5f : 1.0f);
    return f;
}

// Kernel B (fused, R3 structure — best measured at 354.5 µs): float4
// grid-stride copy grid->out_grid with ALIGNED nontemporal stores (chunks
// start at e==3 mod 4; loads take the 4B misalignment). Chunks overlapping
// slot j compute f_grid instead and accumulate loss. nt hints: 420 MB
// stream has zero reuse -> bypass L2 state overhead.
__global__ void __launch_bounds__(256)
copy_fgrid_kernel(const float* __restrict__ grid,
                  float* __restrict__ out_grid,      // out + 1 + NPTS
                  const float* __restrict__ ws_in,
                  float* __restrict__ ws_out,
                  const int* __restrict__ jptr) {
    const int j = *jptr;
    const long long jlo = (long long)j * FG;
    const long long jhi = jlo + FG;

    float s[5];
#pragma unroll
    for (int n = 0; n < 5; ++n) s[n] = ws_in[n];

    float local = 0.0f;
    const long long stride = (long long)gridDim.x * blockDim.x;
    for (long long c = (long long)blockIdx.x * blockDim.x + threadIdx.x;
         c < NCH; c += stride) {
        const long long base = HEAD + c * 4;
        f4 v = (f4)__builtin_nontemporal_load((const f4u*)(grid + base));
        if (base + 3 >= jlo && base < jhi) {
            // rare path: some of the 4 elems lie in slot j -> compute f
#pragma unroll
            for (int q = 0; q < 4; ++q) {
                long long e = base + q;
                if (e >= jlo && e < jhi) {
                    float w4;
                    float f = fgrid_eval(s, (int)(e - jlo), &w4);
                    v[q] = f;
                    local += f * w4;
                }
            }
        }
        __builtin_nontemporal_store(v, (f4*)(out_grid + base));  // 16B-aligned
    }

    // head (e=0,1,2) and tail (e=TAIL_E) handled by a single thread
    if (blockIdx.x == 0 && threadIdx.x == 0) {
        const long long edge[4] = {0, 1, 2, TAIL_E};
#pragma unroll
        for (int t = 0; t < 4; ++t) {
            long long e = edge[t];
            float v = grid[e];
            if (e >= jlo && e < jhi) {
                float w4;
                float f = fgrid_eval(s, (int)(e - jlo), &w4);
                v = f;
                local += f * w4;
            }
            out_grid[e] = v;
        }
    }

    // wave-level reduction of loss contributions, one atomic per wave
#pragma unroll
    for (int off = 32; off > 0; off >>= 1) local += __shfl_down(local, off, 64);
    if ((threadIdx.x & 63) == 0 && local != 0.0f) atomicAdd(&ws_out[6], local);
}

// Kernel C: finalize loss
__global__ void finalize_kernel(const float* __restrict__ ws,
                                float* __restrict__ out) {
    out[0] = ws[6] - 0.5f * ws[5];
}

extern "C" void kernel_launch(void* const* d_in, const int* in_sizes, int n_in,
                              void* d_out, int out_size, void* d_ws, size_t ws_size,
                              hipStream_t stream) {
    const float* x     = (const float*)d_in[0];   // [5,256,256]
    const float* theta = (const float*)d_in[1];   // [1,256,256]
    const float* grid  = (const float*)d_in[2];   // [2000,5,25,7,6,5]
    const int*   jptr  = (const int*)d_in[3];     // scalar

    float* out = (float*)d_out;
    float* ws  = (float*)d_ws;

    // zero reduction scratch (ws is poisoned 0xAA each launch)
    hipMemsetAsync(ws, 0, 7 * sizeof(float), stream);

    // K1: projections + |theta| sum + theta passthrough
    reduce_kernel<<<NPTS / 256, 256, 0, stream>>>(x, theta, out + 1, ws);

    // K2: fused copy + f_grid scatter + loss partial (dst-aligned, nt)
    copy_fgrid_kernel<<<16384, 256, 0, stream>>>(grid, out + 1 + NPTS,
                                                 ws, ws, jptr);

    // K3: finalize loss
    finalize_kernel<<<1, 1, 0, stream>>>(ws, out);
}